// Round 14
// baseline (4652.626 us; speedup 1.0000x reference)
//
#include <hip/hip_runtime.h>
#include <hip/hip_bf16.h>

#define TSTEPS 512
#define NEX 256
#define NIN 128
#define HDIM 256
#define NCOLS 16
#define NBLKCOL 8         // producer blocks per column (2 waves each)

typedef __attribute__((ext_vector_type(8))) short short8;   // 8 bf16 (MFMA A/B frag)
typedef __attribute__((ext_vector_type(4))) float f32x4;    // MFMA C/D frag
typedef __attribute__((ext_vector_type(4))) int i32x4;      // VGPR quad for asm payloads

__device__ __forceinline__ float sig_(float x) {
    return __builtin_amdgcn_rcpf(1.0f + __builtin_amdgcn_exp2f(-1.44269504f * x));
}
__device__ __forceinline__ float tanh_(float x) {
    return 1.0f - 2.0f * __builtin_amdgcn_rcpf(1.0f + __builtin_amdgcn_exp2f(2.88539008f * x));
}

__global__ void zero_ws(unsigned int* p, int n) {
    int i = blockIdx.x * blockDim.x + threadIdx.x;
    if (i < n) p[i] = 0u;
}

// one-time X pre-pack (R8-proven): X[ex][ii][t] f32 -> xp[t][ex][o] bf16
__global__ __launch_bounds__(64) void pack_x(const float* __restrict__ X,
                                             unsigned short* __restrict__ xp) {
    __shared__ __align__(16) unsigned short Ls[16][136];
    const int tid = threadIdx.x;
    const int ex = blockIdx.x >> 5;
    const int t0 = (blockIdx.x & 31) * 16;
#pragma unroll
    for (int s = 0; s < 8; ++s) {
        const int idx = s * 64 + tid;
        const int ii = idx >> 2, tq = idx & 3;
        const float4 v = *(const float4*)(X + ((size_t)ex * NIN + ii) * TSTEPS + t0 + tq * 4);
        const int o = ((ii >> 3) & 3) * 32 + (ii >> 5) * 8 + (ii & 7);
        __hip_bfloat16 b0 = (__hip_bfloat16)v.x, b1 = (__hip_bfloat16)v.y,
                       b2 = (__hip_bfloat16)v.z, b3 = (__hip_bfloat16)v.w;
        Ls[tq * 4 + 0][o] = *(unsigned short*)&b0;
        Ls[tq * 4 + 1][o] = *(unsigned short*)&b1;
        Ls[tq * 4 + 2][o] = *(unsigned short*)&b2;
        Ls[tq * 4 + 3][o] = *(unsigned short*)&b3;
    }
    __syncthreads();
#pragma unroll
    for (int s = 0; s < 4; ++s) {
        const int idx = s * 64 + tid;
        const int tl = idx >> 4, c = idx & 15;
        const short8 v = *(const short8*)&Ls[tl][c * 8];
        *(short8*)(xp + ((size_t)(t0 + tl) * NEX + ex) * NIN + c * 8) = v;
    }
}

// fused poll+data load: 16 x dwordx4 sc0 sc1 (IF$ scope), R11-proven
__device__ __forceinline__ void msg_load16(const char* sb, i32x4* mi) {
    asm volatile(
        "global_load_dwordx4 %0, %16, off sc0 sc1\n\t"
        "global_load_dwordx4 %1, %16, off offset:16 sc0 sc1\n\t"
        "global_load_dwordx4 %2, %16, off offset:128 sc0 sc1\n\t"
        "global_load_dwordx4 %3, %16, off offset:144 sc0 sc1\n\t"
        "global_load_dwordx4 %4, %16, off offset:256 sc0 sc1\n\t"
        "global_load_dwordx4 %5, %16, off offset:272 sc0 sc1\n\t"
        "global_load_dwordx4 %6, %16, off offset:384 sc0 sc1\n\t"
        "global_load_dwordx4 %7, %16, off offset:400 sc0 sc1\n\t"
        "global_load_dwordx4 %8, %16, off offset:512 sc0 sc1\n\t"
        "global_load_dwordx4 %9, %16, off offset:528 sc0 sc1\n\t"
        "global_load_dwordx4 %10, %16, off offset:640 sc0 sc1\n\t"
        "global_load_dwordx4 %11, %16, off offset:656 sc0 sc1\n\t"
        "global_load_dwordx4 %12, %16, off offset:768 sc0 sc1\n\t"
        "global_load_dwordx4 %13, %16, off offset:784 sc0 sc1\n\t"
        "global_load_dwordx4 %14, %16, off offset:896 sc0 sc1\n\t"
        "global_load_dwordx4 %15, %16, off offset:912 sc0 sc1\n\t"
        "s_waitcnt vmcnt(0)"
        : "=&v"(mi[0]), "=&v"(mi[1]), "=&v"(mi[2]), "=&v"(mi[3]),
          "=&v"(mi[4]), "=&v"(mi[5]), "=&v"(mi[6]), "=&v"(mi[7]),
          "=&v"(mi[8]), "=&v"(mi[9]), "=&v"(mi[10]), "=&v"(mi[11]),
          "=&v"(mi[12]), "=&v"(mi[13]), "=&v"(mi[14]), "=&v"(mi[15])
        : "v"(sb) : "memory");
}

// Persistent LSTM: 128 blocks x 128 threads (2 waves). Block b: i=b>>4 (0..7,
// 32-unit tile), j=b&15 (16-ex column). Wave wv: units u0=i*32+wv*16. Lane:
// mrow -> ex=e0+mrow; kg -> units ub=u0+kg*4..+3.
// Message (16B [h01|tag|h23|tag]) per producer-lane at hbuf2[t&1][ex][g=i*8+wv*4+kg].
// Consumer chunk kk (zh[kk], msgs 2kk,2kk+1) comes from EXACTLY block i=kk ->
// in-order arrival pipeline: process chunks 0..7 as their producer block lands
// (fixed order = R11 accumulation order = deterministic), overlapping h-MFMAs
// with straggler wait. Straggler set per step: 8 blocks (was 16).
template<int PX>
__global__ __launch_bounds__(128, 1) void lstm_persist(
    const float* __restrict__ X,     // [256,128,512]
    const float* __restrict__ Wih,   // [1024,128]
    const float* __restrict__ Whh,   // [1024,256]
    const float* __restrict__ bias,  // [1024]
    float* __restrict__ A,           // [512,256,256]
    float* __restrict__ C,           // [512,256,256]
    char* __restrict__ hbuf2,        // [2][256][64] x 16B messages = 512 KB
    const unsigned short* __restrict__ xp)   // [512][256][128] packed bf16 frags
{
    __shared__ __align__(16) __hip_bfloat16 Ws[2][4][16][392];  // 100.4 KB

    const int tid = threadIdx.x;
    const int b = blockIdx.x;
    const int i = b >> 4, j = b & 15;
    const int e0 = j * 16;

    // ---- one-time weight staging: both waves' slices, fp32 -> bf16 ----
    for (int idx = tid; idx < 128 * 96; idx += 128) {
        const int row = idx / 96, q = idx - row * 96;   // row: w*64 + g*16 + ul
        const int w = row >> 6, g = (row >> 4) & 3, ul = row & 15;
        const int u0w = i * 32 + w * 16;
        float4 v;
        int k0;
        if (q < 64) {
            v = *(const float4*)(Whh + (size_t)(g * HDIM + u0w + ul) * HDIM + 4 * q);
            k0 = 4 * q;
        } else {
            v = *(const float4*)(Wih + (size_t)(g * HDIM + u0w + ul) * NIN + 4 * (q - 64));
            k0 = HDIM + 4 * (q - 64);
        }
        Ws[w][g][ul][k0 + 0] = (__hip_bfloat16)v.x;
        Ws[w][g][ul][k0 + 1] = (__hip_bfloat16)v.y;
        Ws[w][g][ul][k0 + 2] = (__hip_bfloat16)v.z;
        Ws[w][g][ul][k0 + 3] = (__hip_bfloat16)v.w;
    }
    __syncthreads();

    const int wv   = tid >> 6;
    const int lane = tid & 63;
    const int mrow = lane & 15;         // D col -> ex_local
    const int kg   = lane >> 4;         // D rows (kg*4+r) -> unit_local
    const int ex   = e0 + mrow;
    const int ub   = i * 32 + wv * 16 + kg * 4;

    short8 wf0[12], wf1[12], wf2[12], wf3[12];
#pragma unroll
    for (int kk = 0; kk < 12; ++kk) {
        wf0[kk] = *(const short8*)&Ws[wv][0][mrow][kk * 32 + kg * 8];
        wf1[kk] = *(const short8*)&Ws[wv][1][mrow][kk * 32 + kg * 8];
        wf2[kk] = *(const short8*)&Ws[wv][2][mrow][kk * 32 + kg * 8];
        wf3[kk] = *(const short8*)&Ws[wv][3][mrow][kk * 32 + kg * 8];
    }
    float bsr[4][4];
#pragma unroll
    for (int g = 0; g < 4; ++g)
#pragma unroll
        for (int r = 0; r < 4; ++r)
            bsr[g][r] = 2.0f * bias[g * HDIM + ub + r];

    const f32x4 Z4 = {0.f, 0.f, 0.f, 0.f};
    float cr[4] = {0.f, 0.f, 0.f, 0.f};

    const size_t cons_off = (size_t)ex * 1024 + (size_t)kg * 32;
    const size_t prod_off = (size_t)ex * 1024 + (size_t)(i * 8 + wv * 4 + kg) * 16;

#define X_GATHER(dst, tt)                                                          \
    {                                                                              \
        const float* xb = X + (size_t)ex * NIN * TSTEPS + (tt);                    \
        _Pragma("unroll")                                                          \
        for (int kk = 0; kk < 4; ++kk) {                                           \
            union { __hip_bfloat16 hh[8]; short8 v; } uxx;                         \
            _Pragma("unroll")                                                      \
            for (int e = 0; e < 8; ++e)                                            \
                uxx.hh[e] = (__hip_bfloat16)xb[(size_t)(kk * 32 + kg * 8 + e) * TSTEPS]; \
            (dst)[kk] = uxx.v;                                                     \
        }                                                                          \
    }

    // prologue: x fragments for t=0
    short8 xf[4];
    if (PX) {
        const unsigned short* xrow = xp + ((size_t)0 * NEX + ex) * NIN + kg * 32;
#pragma unroll
        for (int kk = 0; kk < 4; ++kk) xf[kk] = *(const short8*)(xrow + kk * 8);
    } else {
        X_GATHER(xf, 0);
    }

    for (int t = 0; t < TSTEPS; ++t) {
        // ---- x-part MFMAs: pre-poll (inside the wait window) ----
        f32x4 a0 = Z4, a1 = Z4, a2 = Z4, a3 = Z4;
#pragma unroll
        for (int kk = 0; kk < 4; ++kk) {
            a0 = __builtin_amdgcn_mfma_f32_16x16x32_bf16(wf0[8 + kk], xf[kk], a0, 0, 0, 0);
            a1 = __builtin_amdgcn_mfma_f32_16x16x32_bf16(wf1[8 + kk], xf[kk], a1, 0, 0, 0);
            a2 = __builtin_amdgcn_mfma_f32_16x16x32_bf16(wf2[8 + kk], xf[kk], a2, 0, 0, 0);
            a3 = __builtin_amdgcn_mfma_f32_16x16x32_bf16(wf3[8 + kk], xf[kk], a3, 0, 0, 0);
        }

        if (t > 0) {
            const char* sb = hbuf2 + (size_t)((t - 1) & 1) * (NEX * 64 * 16) + cons_off;
            i32x4 m[16];
            int next = 0;   // in-order chunk pipeline: chunk kk <- producer block kk
            while (next < 8) {
                msg_load16(sb, m);   // fused poll + data (one drain)
                const unsigned int* mu = (const unsigned int*)m;
                while (next < 8) {
                    const unsigned int* q0 = mu + 4 * (2 * next);
                    const unsigned int* q1 = mu + 4 * (2 * next + 1);
                    unsigned int lo = q0[1] < q0[3] ? q0[1] : q0[3];
                    const unsigned int l1 = q1[1] < q1[3] ? q1[1] : q1[3];
                    lo = lo < l1 ? lo : l1;
                    if (!__all(lo == (unsigned int)t)) break;
                    union { unsigned int u[4]; short8 v; } z;
                    z.u[0] = q0[0];
                    z.u[1] = q0[2];
                    z.u[2] = q1[0];
                    z.u[3] = q1[2];
                    a0 = __builtin_amdgcn_mfma_f32_16x16x32_bf16(wf0[next], z.v, a0, 0, 0, 0);
                    a1 = __builtin_amdgcn_mfma_f32_16x16x32_bf16(wf1[next], z.v, a1, 0, 0, 0);
                    a2 = __builtin_amdgcn_mfma_f32_16x16x32_bf16(wf2[next], z.v, a2, 0, 0, 0);
                    a3 = __builtin_amdgcn_mfma_f32_16x16x32_bf16(wf3[next], z.v, a3, 0, 0, 0);
                    ++next;
                }
            }
        }

        // ---- pointwise cell ----
        float hr[4];
#pragma unroll
        for (int r = 0; r < 4; ++r) {
            const float gi = sig_(a0[r] + bsr[0][r]);
            const float gf = sig_(a1[r] + bsr[1][r]);
            const float gg = tanh_(a2[r] + bsr[2][r]);
            const float go = sig_(a3[r] + bsr[3][r]);
            cr[r] = gf * cr[r] + gi * gg;
            hr[r] = go * tanh_(cr[r]);
        }

        // ---- publish: ONE 16B dual-tag message (sc0 sc1), no drain ----
        union { unsigned int u[4]; i32x4 i4; } P;
        __hip_bfloat162 p01(__float2bfloat16(hr[0]), __float2bfloat16(hr[1]));
        __hip_bfloat162 p23(__float2bfloat16(hr[2]), __float2bfloat16(hr[3]));
        P.u[0] = *(unsigned int*)&p01;
        P.u[1] = (unsigned int)(t + 1);
        P.u[2] = *(unsigned int*)&p23;
        P.u[3] = (unsigned int)(t + 1);
        char* dst = hbuf2 + (size_t)(t & 1) * (NEX * 64 * 16) + prod_off;
        asm volatile("global_store_dwordx4 %0, %1, off sc0 sc1"
                     :: "v"(dst), "v"(P.i4) : "memory");

        // ---- shadow: x(t+1) prefetch + outputs ----
        if (t + 1 < TSTEPS) {
            if (PX) {
                const unsigned short* xrow = xp + ((size_t)(t + 1) * NEX + ex) * NIN + kg * 32;
#pragma unroll
                for (int kk = 0; kk < 4; ++kk) xf[kk] = *(const short8*)(xrow + kk * 8);
            } else {
                X_GATHER(xf, t + 1);
            }
        }
        const size_t off = (size_t)t * NEX * HDIM + (size_t)ex * HDIM + ub;
        *(float4*)&A[off] = make_float4(hr[0], hr[1], hr[2], hr[3]);
        *(float4*)&C[off] = make_float4(cr[0], cr[1], cr[2], cr[3]);
    }
#undef X_GATHER
}

extern "C" void kernel_launch(void* const* d_in, const int* in_sizes, int n_in,
                              void* d_out, int out_size, void* d_ws, size_t ws_size,
                              hipStream_t stream) {
    const float* X   = (const float*)d_in[0];
    const float* Wih = (const float*)d_in[1];
    const float* Whh = (const float*)d_in[2];
    const float* b   = (const float*)d_in[3];
    float* A = (float*)d_out;
    float* C = A + (size_t)TSTEPS * NEX * HDIM;

    const size_t hbuf_bytes = (size_t)2 * NEX * 64 * 16;                           // 512 KB
    const size_t xp_bytes   = (size_t)TSTEPS * NEX * NIN * sizeof(unsigned short); // 32 MB

    char* hbuf2 = (char*)d_ws;
    unsigned short* xpw = (unsigned short*)((char*)d_ws + hbuf_bytes);
    const bool px = ws_size >= hbuf_bytes + xp_bytes;

    const int nzero = (int)(hbuf_bytes / 4);
    zero_ws<<<(nzero + 255) / 256, 256, 0, stream>>>((unsigned int*)hbuf2, nzero);
    if (px) pack_x<<<dim3(NEX * 32), dim3(64), 0, stream>>>(X, xpw);

    const unsigned short* xpc = xpw;
    if (px) {
        void* args[] = {(void*)&X, (void*)&Wih, (void*)&Whh, (void*)&b,
                        (void*)&A, (void*)&C, (void*)&hbuf2, (void*)&xpc};
        hipError_t err = hipLaunchCooperativeKernel((const void*)lstm_persist<1>,
                                                    dim3(128), dim3(128), args, 0, stream);
        if (err != hipSuccess) {
            lstm_persist<1><<<dim3(128), dim3(128), 0, stream>>>(X, Wih, Whh, b, A, C, hbuf2, xpc);
        }
    } else {
        void* args[] = {(void*)&X, (void*)&Wih, (void*)&Whh, (void*)&b,
                        (void*)&A, (void*)&C, (void*)&hbuf2, (void*)&xpc};
        hipError_t err = hipLaunchCooperativeKernel((const void*)lstm_persist<0>,
                                                    dim3(128), dim3(128), args, 0, stream);
        if (err != hipSuccess) {
            lstm_persist<0><<<dim3(128), dim3(128), 0, stream>>>(X, Wih, Whh, b, A, C, hbuf2, xpc);
        }
    }
}

// Round 15
// 1521.703 us; speedup vs baseline: 3.0575x; 3.0575x over previous
//
#include <hip/hip_runtime.h>
#include <hip/hip_bf16.h>

#define TSTEPS 512
#define NEX 256
#define NIN 128
#define HDIM 256
#define NCOLS 16
#define NBLKCOL 4        // blocks per column; each owns 64 units via 4 waves

typedef __attribute__((ext_vector_type(8))) short short8;   // 8 bf16 (MFMA A/B frag)
typedef __attribute__((ext_vector_type(4))) float f32x4;    // MFMA C/D frag
typedef __attribute__((ext_vector_type(4))) int i32x4;      // VGPR quad for asm payloads

__device__ __forceinline__ float sig_(float x) {
    return __builtin_amdgcn_rcpf(1.0f + __builtin_amdgcn_exp2f(-1.44269504f * x));
}
__device__ __forceinline__ float tanh_(float x) {
    return 1.0f - 2.0f * __builtin_amdgcn_rcpf(1.0f + __builtin_amdgcn_exp2f(2.88539008f * x));
}

__global__ void zero_ws(unsigned int* p, int n) {
    int i = blockIdx.x * blockDim.x + threadIdx.x;
    if (i < n) p[i] = 0u;
}

// one-time X pre-pack (R8-proven): X[ex][ii][t] f32 -> xp[t][ex][o] bf16
__global__ __launch_bounds__(64) void pack_x(const float* __restrict__ X,
                                             unsigned short* __restrict__ xp) {
    __shared__ __align__(16) unsigned short Ls[16][136];
    const int tid = threadIdx.x;
    const int ex = blockIdx.x >> 5;
    const int t0 = (blockIdx.x & 31) * 16;
#pragma unroll
    for (int s = 0; s < 8; ++s) {
        const int idx = s * 64 + tid;
        const int ii = idx >> 2, tq = idx & 3;
        const float4 v = *(const float4*)(X + ((size_t)ex * NIN + ii) * TSTEPS + t0 + tq * 4);
        const int o = ((ii >> 3) & 3) * 32 + (ii >> 5) * 8 + (ii & 7);
        __hip_bfloat16 b0 = (__hip_bfloat16)v.x, b1 = (__hip_bfloat16)v.y,
                       b2 = (__hip_bfloat16)v.z, b3 = (__hip_bfloat16)v.w;
        Ls[tq * 4 + 0][o] = *(unsigned short*)&b0;
        Ls[tq * 4 + 1][o] = *(unsigned short*)&b1;
        Ls[tq * 4 + 2][o] = *(unsigned short*)&b2;
        Ls[tq * 4 + 3][o] = *(unsigned short*)&b3;
    }
    __syncthreads();
#pragma unroll
    for (int s = 0; s < 4; ++s) {
        const int idx = s * 64 + tid;
        const int tl = idx >> 4, c = idx & 15;
        const short8 v = *(const short8*)&Ls[tl][c * 8];
        *(short8*)(xp + ((size_t)(t0 + tl) * NEX + ex) * NIN + c * 8) = v;
    }
}

// fused poll+data of the 12 REMOTE messages (offsets = remote chunks kk*128, +16),
// retried until all 24 tag words == t. R11 message semantics, 3-block straggler set.
#define POLL12_BODY(O0,O1,O2,O3,O4,O5,O6,O7,O8,O9,O10,O11)                          \
    for (;;) {                                                                      \
        asm volatile(                                                               \
            "global_load_dwordx4 %0, %12, off offset:" #O0 " sc0 sc1\n\t"           \
            "global_load_dwordx4 %1, %12, off offset:" #O1 " sc0 sc1\n\t"           \
            "global_load_dwordx4 %2, %12, off offset:" #O2 " sc0 sc1\n\t"           \
            "global_load_dwordx4 %3, %12, off offset:" #O3 " sc0 sc1\n\t"           \
            "global_load_dwordx4 %4, %12, off offset:" #O4 " sc0 sc1\n\t"           \
            "global_load_dwordx4 %5, %12, off offset:" #O5 " sc0 sc1\n\t"           \
            "global_load_dwordx4 %6, %12, off offset:" #O6 " sc0 sc1\n\t"           \
            "global_load_dwordx4 %7, %12, off offset:" #O7 " sc0 sc1\n\t"           \
            "global_load_dwordx4 %8, %12, off offset:" #O8 " sc0 sc1\n\t"           \
            "global_load_dwordx4 %9, %12, off offset:" #O9 " sc0 sc1\n\t"           \
            "global_load_dwordx4 %10, %12, off offset:" #O10 " sc0 sc1\n\t"         \
            "global_load_dwordx4 %11, %12, off offset:" #O11 " sc0 sc1\n\t"         \
            "s_waitcnt vmcnt(0)"                                                    \
            : "=&v"(m[0]), "=&v"(m[1]), "=&v"(m[2]), "=&v"(m[3]),                   \
              "=&v"(m[4]), "=&v"(m[5]), "=&v"(m[6]), "=&v"(m[7]),                   \
              "=&v"(m[8]), "=&v"(m[9]), "=&v"(m[10]), "=&v"(m[11])                  \
            : "v"(sb) : "memory");                                                  \
        const unsigned int* mu = (const unsigned int*)m;                            \
        unsigned int mn = 0xFFFFFFFFu;                                              \
        _Pragma("unroll")                                                           \
        for (int q = 0; q < 12; ++q) {                                              \
            const unsigned int lo = mu[4*q+1] < mu[4*q+3] ? mu[4*q+1] : mu[4*q+3];  \
            mn = mn < lo ? mn : lo;                                                 \
        }                                                                           \
        if (__all(mn == (unsigned int)t)) break;                                    \
    }

#define HCHUNK_M(c, kk)                                                             \
    {                                                                               \
        union { unsigned int u[4]; short8 v; } z;                                   \
        const unsigned int* q0 = (const unsigned int*)&m[2*(c)];                    \
        const unsigned int* q1 = (const unsigned int*)&m[2*(c)+1];                  \
        z.u[0] = q0[0]; z.u[1] = q0[2]; z.u[2] = q1[0]; z.u[3] = q1[2];             \
        a0 = __builtin_amdgcn_mfma_f32_16x16x32_bf16(wf0[kk], z.v, a0, 0, 0, 0);    \
        a1 = __builtin_amdgcn_mfma_f32_16x16x32_bf16(wf1[kk], z.v, a1, 0, 0, 0);    \
        a2 = __builtin_amdgcn_mfma_f32_16x16x32_bf16(wf2[kk], z.v, a2, 0, 0, 0);    \
        a3 = __builtin_amdgcn_mfma_f32_16x16x32_bf16(wf3[kk], z.v, a3, 0, 0, 0);    \
    }

#define HLOCAL_M(zz, kk)                                                            \
    {                                                                               \
        a0 = __builtin_amdgcn_mfma_f32_16x16x32_bf16(wf0[kk], (zz), a0, 0, 0, 0);   \
        a1 = __builtin_amdgcn_mfma_f32_16x16x32_bf16(wf1[kk], (zz), a1, 0, 0, 0);   \
        a2 = __builtin_amdgcn_mfma_f32_16x16x32_bf16(wf2[kk], (zz), a2, 0, 0, 0);   \
        a3 = __builtin_amdgcn_mfma_f32_16x16x32_bf16(wf3[kk], (zz), a3, 0, 0, 0);   \
    }

// Hierarchical persistent LSTM: 64 blocks = 4 unit-quarters x 16 ex-columns,
// 256 threads = 4 waves. Block b: i=b>>4 (units i*64..+63), j=b&15 (ex e0=j*16).
// Wave wv owns units i*64+wv*16..+15; lane: mrow->ex, kg->4 units ub..ub+3.
// Intra-block h exchange via LDS (Hs parity buffer + one __syncthreads per step).
// Remote h (192 units) via R11's 16B [h01|tag|h23|tag] messages, 12-load fused poll.
template<int PX>
__global__ __launch_bounds__(256, 1) void lstm_persist(
    const float* __restrict__ X,     // [256,128,512]
    const float* __restrict__ Wih,   // [1024,128]
    const float* __restrict__ Whh,   // [1024,256]
    const float* __restrict__ bias,  // [1024]
    float* __restrict__ A,           // [512,256,256]
    float* __restrict__ C,           // [512,256,256]
    char* __restrict__ hbuf2,        // [2][256][64] x 16B messages = 512 KB
    const unsigned short* __restrict__ xp)   // [512][256][128] packed bf16 frags
{
    __shared__ __align__(16) __hip_bfloat16 Ws[4][16][392];   // staging slice, 50.2 KB
    __shared__ __align__(16) unsigned short Hs[2][16][72];    // local h, 4.6 KB

    const int tid = threadIdx.x;
    const int b = blockIdx.x;
    const int i = b >> 4, j = b & 15;     // i: unit quarter (0..3), j: column
    const int e0 = j * 16;

    const int wv   = tid >> 6;
    const int lane = tid & 63;
    const int mrow = lane & 15;           // D col -> ex_local
    const int kg   = lane >> 4;           // D rows (kg*4+r) -> unit_local
    const int ex   = e0 + mrow;
    const int ub   = i * 64 + wv * 16 + kg * 4;

    // ---- one-time weight staging: per-wave slice through shared LDS buffer ----
    short8 wf0[12], wf1[12], wf2[12], wf3[12];
    for (int w = 0; w < 4; ++w) {
        const int u0w = i * 64 + w * 16;
        for (int idx = tid; idx < 64 * 96; idx += 256) {
            const int row = idx / 96, q = idx - row * 96;
            const int g = row >> 4, ul = row & 15;
            float4 v;
            int k0;
            if (q < 64) {
                v = *(const float4*)(Whh + (size_t)(g * HDIM + u0w + ul) * HDIM + 4 * q);
                k0 = 4 * q;
            } else {
                v = *(const float4*)(Wih + (size_t)(g * HDIM + u0w + ul) * NIN + 4 * (q - 64));
                k0 = HDIM + 4 * (q - 64);
            }
            Ws[g][ul][k0 + 0] = (__hip_bfloat16)v.x;
            Ws[g][ul][k0 + 1] = (__hip_bfloat16)v.y;
            Ws[g][ul][k0 + 2] = (__hip_bfloat16)v.z;
            Ws[g][ul][k0 + 3] = (__hip_bfloat16)v.w;
        }
        __syncthreads();
        if (wv == w) {
#pragma unroll
            for (int kk = 0; kk < 12; ++kk) {
                wf0[kk] = *(const short8*)&Ws[0][mrow][kk * 32 + kg * 8];
                wf1[kk] = *(const short8*)&Ws[1][mrow][kk * 32 + kg * 8];
                wf2[kk] = *(const short8*)&Ws[2][mrow][kk * 32 + kg * 8];
                wf3[kk] = *(const short8*)&Ws[3][mrow][kk * 32 + kg * 8];
            }
        }
        __syncthreads();
    }

    float bsr[4][4];
#pragma unroll
    for (int g = 0; g < 4; ++g)
#pragma unroll
        for (int r = 0; r < 4; ++r)
            bsr[g][r] = 2.0f * bias[g * HDIM + ub + r];

    const f32x4 Z4 = {0.f, 0.f, 0.f, 0.f};
    float cr[4] = {0.f, 0.f, 0.f, 0.f};

    const size_t cons_off = (size_t)ex * 1024 + (size_t)kg * 32;
    const size_t prod_off = (size_t)ex * 1024 + (size_t)(i * 16 + wv * 4 + kg) * 16;

#define X_GATHER(dst, tt)                                                          \
    {                                                                              \
        const float* xb = X + (size_t)ex * NIN * TSTEPS + (tt);                    \
        _Pragma("unroll")                                                          \
        for (int kk = 0; kk < 4; ++kk) {                                           \
            union { __hip_bfloat16 hh[8]; short8 v; } uxx;                         \
            _Pragma("unroll")                                                      \
            for (int e = 0; e < 8; ++e)                                            \
                uxx.hh[e] = (__hip_bfloat16)xb[(size_t)(kk * 32 + kg * 8 + e) * TSTEPS]; \
            (dst)[kk] = uxx.v;                                                     \
        }                                                                          \
    }

    // prologue: x fragments for t=0
    short8 xf[4];
    if (PX) {
        const unsigned short* xrow = xp + ((size_t)0 * NEX + ex) * NIN + kg * 32;
#pragma unroll
        for (int kk = 0; kk < 4; ++kk) xf[kk] = *(const short8*)(xrow + kk * 8);
    } else {
        X_GATHER(xf, 0);
    }

    for (int t = 0; t < TSTEPS; ++t) {
        // ---- pre-poll: x-part MFMAs ----
        f32x4 a0 = Z4, a1 = Z4, a2 = Z4, a3 = Z4;
#pragma unroll
        for (int kk = 0; kk < 4; ++kk) {
            a0 = __builtin_amdgcn_mfma_f32_16x16x32_bf16(wf0[8 + kk], xf[kk], a0, 0, 0, 0);
            a1 = __builtin_amdgcn_mfma_f32_16x16x32_bf16(wf1[8 + kk], xf[kk], a1, 0, 0, 0);
            a2 = __builtin_amdgcn_mfma_f32_16x16x32_bf16(wf2[8 + kk], xf[kk], a2, 0, 0, 0);
            a3 = __builtin_amdgcn_mfma_f32_16x16x32_bf16(wf3[8 + kk], xf[kk], a3, 0, 0, 0);
        }

        if (t > 0) {
            // ---- local chunks (our 64 units) from LDS, pre-poll ----
            const int p = (t - 1) & 1;
            const short8 zl0 = *(const short8*)&Hs[p][mrow][kg * 8];
            const short8 zl1 = *(const short8*)&Hs[p][mrow][32 + kg * 8];
            const char* sb = hbuf2 + (size_t)((t - 1) & 1) * (NEX * 64 * 16) + cons_off;
            i32x4 m[12];
            if (i == 0) {
                HLOCAL_M(zl0, 0) HLOCAL_M(zl1, 1)
                POLL12_BODY(256,272,384,400,512,528,640,656,768,784,896,912)
                HCHUNK_M(0,2) HCHUNK_M(1,3) HCHUNK_M(2,4) HCHUNK_M(3,5) HCHUNK_M(4,6) HCHUNK_M(5,7)
            } else if (i == 1) {
                HLOCAL_M(zl0, 2) HLOCAL_M(zl1, 3)
                POLL12_BODY(0,16,128,144,512,528,640,656,768,784,896,912)
                HCHUNK_M(0,0) HCHUNK_M(1,1) HCHUNK_M(2,4) HCHUNK_M(3,5) HCHUNK_M(4,6) HCHUNK_M(5,7)
            } else if (i == 2) {
                HLOCAL_M(zl0, 4) HLOCAL_M(zl1, 5)
                POLL12_BODY(0,16,128,144,256,272,384,400,768,784,896,912)
                HCHUNK_M(0,0) HCHUNK_M(1,1) HCHUNK_M(2,2) HCHUNK_M(3,3) HCHUNK_M(4,6) HCHUNK_M(5,7)
            } else {
                HLOCAL_M(zl0, 6) HLOCAL_M(zl1, 7)
                POLL12_BODY(0,16,128,144,256,272,384,400,512,528,640,656)
                HCHUNK_M(0,0) HCHUNK_M(1,1) HCHUNK_M(2,2) HCHUNK_M(3,3) HCHUNK_M(4,4) HCHUNK_M(5,5)
            }
        }

        // ---- pointwise cell ----
        float hr[4];
#pragma unroll
        for (int r = 0; r < 4; ++r) {
            const float gi = sig_(a0[r] + bsr[0][r]);
            const float gf = sig_(a1[r] + bsr[1][r]);
            const float gg = tanh_(a2[r] + bsr[2][r]);
            const float go = sig_(a3[r] + bsr[3][r]);
            cr[r] = gf * cr[r] + gi * gg;
            hr[r] = go * tanh_(cr[r]);
        }

        // ---- publish remote message (one sc0 sc1 dwordx4) + local LDS h ----
        union { unsigned int u[4]; i32x4 i4; } P;
        __hip_bfloat162 p01(__float2bfloat16(hr[0]), __float2bfloat16(hr[1]));
        __hip_bfloat162 p23(__float2bfloat16(hr[2]), __float2bfloat16(hr[3]));
        P.u[0] = *(unsigned int*)&p01;
        P.u[1] = (unsigned int)(t + 1);
        P.u[2] = *(unsigned int*)&p23;
        P.u[3] = (unsigned int)(t + 1);
        char* dst = hbuf2 + (size_t)(t & 1) * (NEX * 64 * 16) + prod_off;
        asm volatile("global_store_dwordx4 %0, %1, off sc0 sc1"
                     :: "v"(dst), "v"(P.i4) : "memory");
        union { unsigned int u2[2]; unsigned long long u8; } HL;
        HL.u2[0] = P.u[0];
        HL.u2[1] = P.u[2];
        *(unsigned long long*)&Hs[t & 1][mrow][wv * 16 + kg * 4] = HL.u8;

        // ---- shadow: x(t+1) prefetch + outputs; then intra-block barrier ----
        if (t + 1 < TSTEPS) {
            if (PX) {
                const unsigned short* xrow = xp + ((size_t)(t + 1) * NEX + ex) * NIN + kg * 32;
#pragma unroll
                for (int kk = 0; kk < 4; ++kk) xf[kk] = *(const short8*)(xrow + kk * 8);
            } else {
                X_GATHER(xf, t + 1);
            }
        }
        const size_t off = (size_t)t * NEX * HDIM + (size_t)ex * HDIM + ub;
        *(float4*)&A[off] = make_float4(hr[0], hr[1], hr[2], hr[3]);
        *(float4*)&C[off] = make_float4(cr[0], cr[1], cr[2], cr[3]);

        __syncthreads();   // Hs[t&1] complete before any wave reads it at t+1
    }
#undef X_GATHER
}

extern "C" void kernel_launch(void* const* d_in, const int* in_sizes, int n_in,
                              void* d_out, int out_size, void* d_ws, size_t ws_size,
                              hipStream_t stream) {
    const float* X   = (const float*)d_in[0];
    const float* Wih = (const float*)d_in[1];
    const float* Whh = (const float*)d_in[2];
    const float* b   = (const float*)d_in[3];
    float* A = (float*)d_out;
    float* C = A + (size_t)TSTEPS * NEX * HDIM;

    const size_t hbuf_bytes = (size_t)2 * NEX * 64 * 16;                           // 512 KB
    const size_t xp_bytes   = (size_t)TSTEPS * NEX * NIN * sizeof(unsigned short); // 32 MB

    char* hbuf2 = (char*)d_ws;
    unsigned short* xpw = (unsigned short*)((char*)d_ws + hbuf_bytes);
    const bool px = ws_size >= hbuf_bytes + xp_bytes;

    const int nzero = (int)(hbuf_bytes / 4);
    zero_ws<<<(nzero + 255) / 256, 256, 0, stream>>>((unsigned int*)hbuf2, nzero);
    if (px) pack_x<<<dim3(NEX * 32), dim3(64), 0, stream>>>(X, xpw);

    const unsigned short* xpc = xpw;
    if (px) {
        void* args[] = {(void*)&X, (void*)&Wih, (void*)&Whh, (void*)&b,
                        (void*)&A, (void*)&C, (void*)&hbuf2, (void*)&xpc};
        hipError_t err = hipLaunchCooperativeKernel((const void*)lstm_persist<1>,
                                                    dim3(64), dim3(256), args, 0, stream);
        if (err != hipSuccess) {
            lstm_persist<1><<<dim3(64), dim3(256), 0, stream>>>(X, Wih, Whh, b, A, C, hbuf2, xpc);
        }
    } else {
        void* args[] = {(void*)&X, (void*)&Wih, (void*)&Whh, (void*)&b,
                        (void*)&A, (void*)&C, (void*)&hbuf2, (void*)&xpc};
        hipError_t err = hipLaunchCooperativeKernel((const void*)lstm_persist<0>,
                                                    dim3(64), dim3(256), args, 0, stream);
        if (err != hipSuccess) {
            lstm_persist<0><<<dim3(64), dim3(256), 0, stream>>>(X, Wih, Whh, b, A, C, hbuf2, xpc);
        }
    }
}

// Round 16
// 932.502 us; speedup vs baseline: 4.9894x; 1.6318x over previous
//
#include <hip/hip_runtime.h>
#include <hip/hip_bf16.h>

#define TSTEPS 512
#define NEX 256
#define NIN 128
#define HDIM 256
#define NCOLS 16
#define NROWBLK 16

typedef __attribute__((ext_vector_type(8))) short short8;   // 8 bf16 (MFMA A/B frag)
typedef __attribute__((ext_vector_type(4))) float f32x4;    // MFMA C/D frag
typedef __attribute__((ext_vector_type(4))) int i32x4;      // VGPR quad for asm payloads

__device__ __forceinline__ float sig_(float x) {
    return __builtin_amdgcn_rcpf(1.0f + __builtin_amdgcn_exp2f(-1.44269504f * x));
}
__device__ __forceinline__ float tanh_(float x) {
    return 1.0f - 2.0f * __builtin_amdgcn_rcpf(1.0f + __builtin_amdgcn_exp2f(2.88539008f * x));
}

__global__ void zero_ws(unsigned int* p, int n) {
    int i = blockIdx.x * blockDim.x + threadIdx.x;
    if (i < n) p[i] = 0u;
}

// one-time X pre-pack (R8-proven): X[ex][ii][t] f32 -> xp[t][ex][o] bf16
__global__ __launch_bounds__(64) void pack_x(const float* __restrict__ X,
                                             unsigned short* __restrict__ xp) {
    __shared__ __align__(16) unsigned short Ls[16][136];
    const int tid = threadIdx.x;
    const int ex = blockIdx.x >> 5;
    const int t0 = (blockIdx.x & 31) * 16;
#pragma unroll
    for (int s = 0; s < 8; ++s) {
        const int idx = s * 64 + tid;
        const int ii = idx >> 2, tq = idx & 3;
        const float4 v = *(const float4*)(X + ((size_t)ex * NIN + ii) * TSTEPS + t0 + tq * 4);
        const int o = ((ii >> 3) & 3) * 32 + (ii >> 5) * 8 + (ii & 7);
        __hip_bfloat16 b0 = (__hip_bfloat16)v.x, b1 = (__hip_bfloat16)v.y,
                       b2 = (__hip_bfloat16)v.z, b3 = (__hip_bfloat16)v.w;
        Ls[tq * 4 + 0][o] = *(unsigned short*)&b0;
        Ls[tq * 4 + 1][o] = *(unsigned short*)&b1;
        Ls[tq * 4 + 2][o] = *(unsigned short*)&b2;
        Ls[tq * 4 + 3][o] = *(unsigned short*)&b3;
    }
    __syncthreads();
#pragma unroll
    for (int s = 0; s < 4; ++s) {
        const int idx = s * 64 + tid;
        const int tl = idx >> 4, c = idx & 15;
        const short8 v = *(const short8*)&Ls[tl][c * 8];
        *(short8*)(xp + ((size_t)(t0 + tl) * NEX + ex) * NIN + c * 8) = v;
    }
}

// fused poll+data: 16 x dwordx4 sc0 sc1 at one base + m*256 offsets (coalesced layout)
__device__ __forceinline__ void msg_load16c(const char* sb, i32x4* mi) {
    asm volatile(
        "global_load_dwordx4 %0, %16, off sc0 sc1\n\t"
        "global_load_dwordx4 %1, %16, off offset:256 sc0 sc1\n\t"
        "global_load_dwordx4 %2, %16, off offset:512 sc0 sc1\n\t"
        "global_load_dwordx4 %3, %16, off offset:768 sc0 sc1\n\t"
        "global_load_dwordx4 %4, %16, off offset:1024 sc0 sc1\n\t"
        "global_load_dwordx4 %5, %16, off offset:1280 sc0 sc1\n\t"
        "global_load_dwordx4 %6, %16, off offset:1536 sc0 sc1\n\t"
        "global_load_dwordx4 %7, %16, off offset:1792 sc0 sc1\n\t"
        "global_load_dwordx4 %8, %16, off offset:2048 sc0 sc1\n\t"
        "global_load_dwordx4 %9, %16, off offset:2304 sc0 sc1\n\t"
        "global_load_dwordx4 %10, %16, off offset:2560 sc0 sc1\n\t"
        "global_load_dwordx4 %11, %16, off offset:2816 sc0 sc1\n\t"
        "global_load_dwordx4 %12, %16, off offset:3072 sc0 sc1\n\t"
        "global_load_dwordx4 %13, %16, off offset:3328 sc0 sc1\n\t"
        "global_load_dwordx4 %14, %16, off offset:3584 sc0 sc1\n\t"
        "global_load_dwordx4 %15, %16, off offset:3840 sc0 sc1\n\t"
        "s_waitcnt vmcnt(0)"
        : "=&v"(mi[0]), "=&v"(mi[1]), "=&v"(mi[2]), "=&v"(mi[3]),
          "=&v"(mi[4]), "=&v"(mi[5]), "=&v"(mi[6]), "=&v"(mi[7]),
          "=&v"(mi[8]), "=&v"(mi[9]), "=&v"(mi[10]), "=&v"(mi[11]),
          "=&v"(mi[12]), "=&v"(mi[13]), "=&v"(mi[14]), "=&v"(mi[15])
        : "v"(sb) : "memory");
}

__device__ __forceinline__ unsigned int tagmin16(const i32x4* mi) {
    const unsigned int* u = (const unsigned int*)mi;
    unsigned int mn = 0xFFFFFFFFu;
#pragma unroll
    for (int q = 0; q < 16; ++q) {
        const unsigned int lo = u[4 * q + 1] < u[4 * q + 3] ? u[4 * q + 1] : u[4 * q + 3];
        mn = mn < lo ? mn : lo;
    }
    return mn;
}

// Persistent LSTM, R11 protocol + coalesced message layout + x-MFMAs pre-poll.
// 256 blocks = 16 unit-tiles x 16 ex-columns; block b: i=b>>4 (u0=i*16), j=b&15 (e0=j*16).
// Lane: mrow=l&15 -> ex (D col); kg=l>>4 -> units ub=u0+4kg..+3 (D rows).
// Message (16B [h01|tag|h23|tag]) for producer (i,kg_p), consumer-indexed layout:
//   slot (kgc, m): kgc = 2(i&1)+(kg_p>>1), m = 2(i>>1)+(kg_p&1)
//   addr = parity*256KB + j*16KB + kgc*4KB + m*256 + exl*16
// Consumer lane (exl,kg): base = slab + kg*4KB + exl*16, loads m=0..15 at m*256 —
// per instruction the wave touches 4 contiguous 256B regions (16 full lines; ~2x
// fewer IF$ transactions than R11's strided layout). Slot m maps to chunk kk=m>>1,
// half d=m&1 — identical consumption order to R11 (deterministic).
template<int PX>
__global__ __launch_bounds__(64, 1) void lstm_persist(
    const float* __restrict__ X,     // [256,128,512]
    const float* __restrict__ Wih,   // [1024,128]
    const float* __restrict__ Whh,   // [1024,256]
    const float* __restrict__ bias,  // [1024]
    float* __restrict__ A,           // [512,256,256]
    float* __restrict__ C,           // [512,256,256]
    char* __restrict__ hbuf2,        // [2][16][4][16][16] x 16B = 512 KB
    const unsigned short* __restrict__ xp)   // [512][256][128] packed bf16 frags
{
    __shared__ __align__(16) __hip_bfloat16 Ws[4][16][392];  // 50.2 KB

    const int tid = threadIdx.x;
    const int b = blockIdx.x;
    const int i = b >> 4, j = b & 15;
    const int u0 = i * 16, e0 = j * 16;

    // one-time weight staging: fp32 -> bf16 LDS [gate][unit_local][k]
    for (int idx = tid; idx < 64 * 96; idx += 64) {
        const int row = idx / 96, q = idx - row * 96;
        const int g = row >> 4, ul = row & 15;
        float4 v;
        int k0;
        if (q < 64) {
            v = *(const float4*)(Whh + (size_t)(g * HDIM + u0 + ul) * HDIM + 4 * q);
            k0 = 4 * q;
        } else {
            v = *(const float4*)(Wih + (size_t)(g * HDIM + u0 + ul) * NIN + 4 * (q - 64));
            k0 = HDIM + 4 * (q - 64);
        }
        Ws[g][ul][k0 + 0] = (__hip_bfloat16)v.x;
        Ws[g][ul][k0 + 1] = (__hip_bfloat16)v.y;
        Ws[g][ul][k0 + 2] = (__hip_bfloat16)v.z;
        Ws[g][ul][k0 + 3] = (__hip_bfloat16)v.w;
    }
    __syncthreads();

    const int mrow = tid & 15;          // D col -> ex_local
    const int kg   = tid >> 4;          // D rows (kg*4+r) -> unit_local
    const int ex   = e0 + mrow;
    const int ub   = u0 + kg * 4;

    short8 wf0[12], wf1[12], wf2[12], wf3[12];
#pragma unroll
    for (int kk = 0; kk < 12; ++kk) {
        wf0[kk] = *(const short8*)&Ws[0][mrow][kk * 32 + kg * 8];
        wf1[kk] = *(const short8*)&Ws[1][mrow][kk * 32 + kg * 8];
        wf2[kk] = *(const short8*)&Ws[2][mrow][kk * 32 + kg * 8];
        wf3[kk] = *(const short8*)&Ws[3][mrow][kk * 32 + kg * 8];
    }
    float bsr[4][4];
#pragma unroll
    for (int g = 0; g < 4; ++g)
#pragma unroll
        for (int r = 0; r < 4; ++r)
            bsr[g][r] = 2.0f * bias[g * HDIM + ub + r];

    const f32x4 Z4 = {0.f, 0.f, 0.f, 0.f};
    float cr[4] = {0.f, 0.f, 0.f, 0.f};

    // coalesced message layout (parity slab = 256 KB)
    const int kgc   = 2 * (i & 1) + (kg >> 1);
    const int mprod = 2 * (i >> 1) + (kg & 1);
    const size_t PSTRIDE  = (size_t)NCOLS * 16384;
    const size_t cons_off = (size_t)j * 16384 + (size_t)kg * 4096 + (size_t)mrow * 16;
    const size_t prod_off = (size_t)j * 16384 + (size_t)kgc * 4096
                          + (size_t)mprod * 256 + (size_t)mrow * 16;

#define X_GATHER(dst, tt)                                                          \
    {                                                                              \
        const float* xb = X + (size_t)ex * NIN * TSTEPS + (tt);                    \
        _Pragma("unroll")                                                          \
        for (int kk = 0; kk < 4; ++kk) {                                           \
            union { __hip_bfloat16 hh[8]; short8 v; } uxx;                         \
            _Pragma("unroll")                                                      \
            for (int e = 0; e < 8; ++e)                                            \
                uxx.hh[e] = (__hip_bfloat16)xb[(size_t)(kk * 32 + kg * 8 + e) * TSTEPS]; \
            (dst)[kk] = uxx.v;                                                     \
        }                                                                          \
    }

    // prologue: x fragments + xa for t=0
    short8 xf[4];
    if (PX) {
        const unsigned short* xrow = xp + ((size_t)0 * NEX + ex) * NIN + kg * 32;
#pragma unroll
        for (int kk = 0; kk < 4; ++kk) xf[kk] = *(const short8*)(xrow + kk * 8);
    } else {
        X_GATHER(xf, 0);
    }
    f32x4 xa0 = Z4, xa1 = Z4, xa2 = Z4, xa3 = Z4;
#pragma unroll
    for (int kk = 0; kk < 4; ++kk) {
        xa0 = __builtin_amdgcn_mfma_f32_16x16x32_bf16(wf0[8 + kk], xf[kk], xa0, 0, 0, 0);
        xa1 = __builtin_amdgcn_mfma_f32_16x16x32_bf16(wf1[8 + kk], xf[kk], xa1, 0, 0, 0);
        xa2 = __builtin_amdgcn_mfma_f32_16x16x32_bf16(wf2[8 + kk], xf[kk], xa2, 0, 0, 0);
        xa3 = __builtin_amdgcn_mfma_f32_16x16x32_bf16(wf3[8 + kk], xf[kk], xa3, 0, 0, 0);
    }

    for (int t = 0; t < TSTEPS; ++t) {
        f32x4 a0 = xa0, a1 = xa1, a2 = xa2, a3 = xa3;   // x part pre-accumulated

        if (t > 0) {
            const char* sb = hbuf2 + (size_t)((t - 1) & 1) * PSTRIDE + cons_off;
            i32x4 m[16];
            for (;;) {
                msg_load16c(sb, m);   // fused poll + data (coalesced, one drain)
                if (__all(tagmin16(m) == (unsigned int)t)) break;
            }
            const unsigned int* mu = (const unsigned int*)m;
#pragma unroll
            for (int kk = 0; kk < 8; ++kk) {
                union { unsigned int u[4]; short8 v; } z;
                z.u[0] = mu[4 * (2 * kk) + 0];
                z.u[1] = mu[4 * (2 * kk) + 2];
                z.u[2] = mu[4 * (2 * kk + 1) + 0];
                z.u[3] = mu[4 * (2 * kk + 1) + 2];
                a0 = __builtin_amdgcn_mfma_f32_16x16x32_bf16(wf0[kk], z.v, a0, 0, 0, 0);
                a1 = __builtin_amdgcn_mfma_f32_16x16x32_bf16(wf1[kk], z.v, a1, 0, 0, 0);
                a2 = __builtin_amdgcn_mfma_f32_16x16x32_bf16(wf2[kk], z.v, a2, 0, 0, 0);
                a3 = __builtin_amdgcn_mfma_f32_16x16x32_bf16(wf3[kk], z.v, a3, 0, 0, 0);
            }
        }

        // ---- pointwise cell ----
        float hr[4];
#pragma unroll
        for (int r = 0; r < 4; ++r) {
            const float gi = sig_(a0[r] + bsr[0][r]);
            const float gf = sig_(a1[r] + bsr[1][r]);
            const float gg = tanh_(a2[r] + bsr[2][r]);
            const float go = sig_(a3[r] + bsr[3][r]);
            cr[r] = gf * cr[r] + gi * gg;
            hr[r] = go * tanh_(cr[r]);
        }

        // ---- publish: ONE 16B dual-tag message (sc0 sc1), coalesced slot ----
        union { unsigned int u[4]; i32x4 i4; } P;
        __hip_bfloat162 p01(__float2bfloat16(hr[0]), __float2bfloat16(hr[1]));
        __hip_bfloat162 p23(__float2bfloat16(hr[2]), __float2bfloat16(hr[3]));
        P.u[0] = *(unsigned int*)&p01;
        P.u[1] = (unsigned int)(t + 1);
        P.u[2] = *(unsigned int*)&p23;
        P.u[3] = (unsigned int)(t + 1);
        char* dst = hbuf2 + (size_t)(t & 1) * PSTRIDE + prod_off;
        asm volatile("global_store_dwordx4 %0, %1, off sc0 sc1"
                     :: "v"(dst), "v"(P.i4) : "memory");

        // ---- shadow: outputs + x(t+1) prefetch + x-MFMAs for t+1 ----
        const size_t off = (size_t)t * NEX * HDIM + (size_t)ex * HDIM + ub;
        *(float4*)&A[off] = make_float4(hr[0], hr[1], hr[2], hr[3]);
        *(float4*)&C[off] = make_float4(cr[0], cr[1], cr[2], cr[3]);
        if (t + 1 < TSTEPS) {
            if (PX) {
                const unsigned short* xrow = xp + ((size_t)(t + 1) * NEX + ex) * NIN + kg * 32;
#pragma unroll
                for (int kk = 0; kk < 4; ++kk) xf[kk] = *(const short8*)(xrow + kk * 8);
            } else {
                X_GATHER(xf, t + 1);
            }
            xa0 = Z4; xa1 = Z4; xa2 = Z4; xa3 = Z4;
#pragma unroll
            for (int kk = 0; kk < 4; ++kk) {
                xa0 = __builtin_amdgcn_mfma_f32_16x16x32_bf16(wf0[8 + kk], xf[kk], xa0, 0, 0, 0);
                xa1 = __builtin_amdgcn_mfma_f32_16x16x32_bf16(wf1[8 + kk], xf[kk], xa1, 0, 0, 0);
                xa2 = __builtin_amdgcn_mfma_f32_16x16x32_bf16(wf2[8 + kk], xf[kk], xa2, 0, 0, 0);
                xa3 = __builtin_amdgcn_mfma_f32_16x16x32_bf16(wf3[8 + kk], xf[kk], xa3, 0, 0, 0);
            }
        }
    }
#undef X_GATHER
}

extern "C" void kernel_launch(void* const* d_in, const int* in_sizes, int n_in,
                              void* d_out, int out_size, void* d_ws, size_t ws_size,
                              hipStream_t stream) {
    const float* X   = (const float*)d_in[0];
    const float* Wih = (const float*)d_in[1];
    const float* Whh = (const float*)d_in[2];
    const float* b   = (const float*)d_in[3];
    float* A = (float*)d_out;
    float* C = A + (size_t)TSTEPS * NEX * HDIM;

    const size_t hbuf_bytes = (size_t)2 * NCOLS * 16384;                           // 512 KB
    const size_t xp_bytes   = (size_t)TSTEPS * NEX * NIN * sizeof(unsigned short); // 32 MB

    char* hbuf2 = (char*)d_ws;
    unsigned short* xpw = (unsigned short*)((char*)d_ws + hbuf_bytes);
    const bool px = ws_size >= hbuf_bytes + xp_bytes;

    const int nzero = (int)(hbuf_bytes / 4);
    zero_ws<<<(nzero + 255) / 256, 256, 0, stream>>>((unsigned int*)hbuf2, nzero);
    if (px) pack_x<<<dim3(NEX * 32), dim3(64), 0, stream>>>(X, xpw);

    const unsigned short* xpc = xpw;
    if (px) {
        void* args[] = {(void*)&X, (void*)&Wih, (void*)&Whh, (void*)&b,
                        (void*)&A, (void*)&C, (void*)&hbuf2, (void*)&xpc};
        hipError_t err = hipLaunchCooperativeKernel((const void*)lstm_persist<1>,
                                                    dim3(256), dim3(64), args, 0, stream);
        if (err != hipSuccess) {
            lstm_persist<1><<<dim3(256), dim3(64), 0, stream>>>(X, Wih, Whh, b, A, C, hbuf2, xpc);
        }
    } else {
        void* args[] = {(void*)&X, (void*)&Wih, (void*)&Whh, (void*)&b,
                        (void*)&A, (void*)&C, (void*)&hbuf2, (void*)&xpc};
        hipError_t err = hipLaunchCooperativeKernel((const void*)lstm_persist<0>,
                                                    dim3(256), dim3(64), args, 0, stream);
        if (err != hipSuccess) {
            lstm_persist<0><<<dim3(256), dim3(64), 0, stream>>>(X, Wih, Whh, b, A, C, hbuf2, xpc);
        }
    }
}

// Round 17
// 930.119 us; speedup vs baseline: 5.0022x; 1.0026x over previous
//
#include <hip/hip_runtime.h>
#include <hip/hip_bf16.h>

#define TSTEPS 512
#define NEX 256
#define NIN 128
#define HDIM 256
#define NCOLS 16
#define NROWBLK 16

typedef __attribute__((ext_vector_type(8))) short short8;   // 8 bf16 (MFMA A/B frag)
typedef __attribute__((ext_vector_type(4))) float f32x4;    // MFMA C/D frag
typedef __attribute__((ext_vector_type(4))) int i32x4;      // VGPR quad for asm payloads

__device__ __forceinline__ float sig_(float x) {
    return __builtin_amdgcn_rcpf(1.0f + __builtin_amdgcn_exp2f(-1.44269504f * x));
}
__device__ __forceinline__ float tanh_(float x) {
    return 1.0f - 2.0f * __builtin_amdgcn_rcpf(1.0f + __builtin_amdgcn_exp2f(2.88539008f * x));
}

__global__ void zero_ws(unsigned int* p, int n) {
    int i = blockIdx.x * blockDim.x + threadIdx.x;
    if (i < n) p[i] = 0u;
}

// one-time X pre-pack (R8-proven): X[ex][ii][t] f32 -> xp[t][ex][o] bf16
__global__ __launch_bounds__(64) void pack_x(const float* __restrict__ X,
                                             unsigned short* __restrict__ xp) {
    __shared__ __align__(16) unsigned short Ls[16][136];
    const int tid = threadIdx.x;
    const int ex = blockIdx.x >> 5;
    const int t0 = (blockIdx.x & 31) * 16;
#pragma unroll
    for (int s = 0; s < 8; ++s) {
        const int idx = s * 64 + tid;
        const int ii = idx >> 2, tq = idx & 3;
        const float4 v = *(const float4*)(X + ((size_t)ex * NIN + ii) * TSTEPS + t0 + tq * 4);
        const int o = ((ii >> 3) & 3) * 32 + (ii >> 5) * 8 + (ii & 7);
        __hip_bfloat16 b0 = (__hip_bfloat16)v.x, b1 = (__hip_bfloat16)v.y,
                       b2 = (__hip_bfloat16)v.z, b3 = (__hip_bfloat16)v.w;
        Ls[tq * 4 + 0][o] = *(unsigned short*)&b0;
        Ls[tq * 4 + 1][o] = *(unsigned short*)&b1;
        Ls[tq * 4 + 2][o] = *(unsigned short*)&b2;
        Ls[tq * 4 + 3][o] = *(unsigned short*)&b3;
    }
    __syncthreads();
#pragma unroll
    for (int s = 0; s < 4; ++s) {
        const int idx = s * 64 + tid;
        const int tl = idx >> 4, c = idx & 15;
        const short8 v = *(const short8*)&Ls[tl][c * 8];
        *(short8*)(xp + ((size_t)(t0 + tl) * NEX + ex) * NIN + c * 8) = v;
    }
}

// fused poll+data: 16 x dwordx4 sc0 sc1 at one base + m*256 offsets (coalesced layout)
__device__ __forceinline__ void msg_load16c(const char* sb, i32x4* mi) {
    asm volatile(
        "global_load_dwordx4 %0, %16, off sc0 sc1\n\t"
        "global_load_dwordx4 %1, %16, off offset:256 sc0 sc1\n\t"
        "global_load_dwordx4 %2, %16, off offset:512 sc0 sc1\n\t"
        "global_load_dwordx4 %3, %16, off offset:768 sc0 sc1\n\t"
        "global_load_dwordx4 %4, %16, off offset:1024 sc0 sc1\n\t"
        "global_load_dwordx4 %5, %16, off offset:1280 sc0 sc1\n\t"
        "global_load_dwordx4 %6, %16, off offset:1536 sc0 sc1\n\t"
        "global_load_dwordx4 %7, %16, off offset:1792 sc0 sc1\n\t"
        "global_load_dwordx4 %8, %16, off offset:2048 sc0 sc1\n\t"
        "global_load_dwordx4 %9, %16, off offset:2304 sc0 sc1\n\t"
        "global_load_dwordx4 %10, %16, off offset:2560 sc0 sc1\n\t"
        "global_load_dwordx4 %11, %16, off offset:2816 sc0 sc1\n\t"
        "global_load_dwordx4 %12, %16, off offset:3072 sc0 sc1\n\t"
        "global_load_dwordx4 %13, %16, off offset:3328 sc0 sc1\n\t"
        "global_load_dwordx4 %14, %16, off offset:3584 sc0 sc1\n\t"
        "global_load_dwordx4 %15, %16, off offset:3840 sc0 sc1\n\t"
        "s_waitcnt vmcnt(0)"
        : "=&v"(mi[0]), "=&v"(mi[1]), "=&v"(mi[2]), "=&v"(mi[3]),
          "=&v"(mi[4]), "=&v"(mi[5]), "=&v"(mi[6]), "=&v"(mi[7]),
          "=&v"(mi[8]), "=&v"(mi[9]), "=&v"(mi[10]), "=&v"(mi[11]),
          "=&v"(mi[12]), "=&v"(mi[13]), "=&v"(mi[14]), "=&v"(mi[15])
        : "v"(sb) : "memory");
}

__device__ __forceinline__ unsigned int tagmin16(const i32x4* mi) {
    const unsigned int* u = (const unsigned int*)mi;
    unsigned int mn = 0xFFFFFFFFu;
#pragma unroll
    for (int q = 0; q < 16; ++q) {
        const unsigned int lo = u[4 * q + 1] < u[4 * q + 3] ? u[4 * q + 1] : u[4 * q + 3];
        mn = mn < lo ? mn : lo;
    }
    return mn;
}

// Persistent LSTM, R16 + register-pinned weights.
// 256 blocks = 16 unit-tiles x 16 ex-columns; block b: i=b>>4 (u0=i*16), j=b&15 (e0=j*16).
// Lane: mrow=l&15 -> ex (D col); kg=l>>4 -> units ub=u0+4kg..+3 (D rows).
// Coalesced message layout (R16): slot (kgc,m): kgc=2(i&1)+(kg>>1), m=2(i>>1)+(kg&1);
// addr = parity*256KB + j*16KB + kgc*4KB + m*256 + exl*16. Consumer: one base +
// m*256 offsets -> 4 contiguous 256B regions per instruction (full lines).
// NEW: all 48 weight fragments + bias pass through a no-op "+v" asm after load ->
// origin becomes opaque -> compiler cannot rematerialize them from LDS inside the
// loop (R16's VGPR_Count=164 < 192 proved it was refilling on the critical path).
template<int PX>
__global__ __launch_bounds__(64, 1) void lstm_persist(
    const float* __restrict__ X,     // [256,128,512]
    const float* __restrict__ Wih,   // [1024,128]
    const float* __restrict__ Whh,   // [1024,256]
    const float* __restrict__ bias,  // [1024]
    float* __restrict__ A,           // [512,256,256]
    float* __restrict__ C,           // [512,256,256]
    char* __restrict__ hbuf2,        // [2][16][4][16][16] x 16B = 512 KB
    const unsigned short* __restrict__ xp)   // [512][256][128] packed bf16 frags
{
    __shared__ __align__(16) __hip_bfloat16 Ws[4][16][392];  // 50.2 KB

    const int tid = threadIdx.x;
    const int b = blockIdx.x;
    const int i = b >> 4, j = b & 15;
    const int u0 = i * 16, e0 = j * 16;

    // one-time weight staging: fp32 -> bf16 LDS [gate][unit_local][k]
    for (int idx = tid; idx < 64 * 96; idx += 64) {
        const int row = idx / 96, q = idx - row * 96;
        const int g = row >> 4, ul = row & 15;
        float4 v;
        int k0;
        if (q < 64) {
            v = *(const float4*)(Whh + (size_t)(g * HDIM + u0 + ul) * HDIM + 4 * q);
            k0 = 4 * q;
        } else {
            v = *(const float4*)(Wih + (size_t)(g * HDIM + u0 + ul) * NIN + 4 * (q - 64));
            k0 = HDIM + 4 * (q - 64);
        }
        Ws[g][ul][k0 + 0] = (__hip_bfloat16)v.x;
        Ws[g][ul][k0 + 1] = (__hip_bfloat16)v.y;
        Ws[g][ul][k0 + 2] = (__hip_bfloat16)v.z;
        Ws[g][ul][k0 + 3] = (__hip_bfloat16)v.w;
    }
    __syncthreads();

    const int mrow = tid & 15;          // D col -> ex_local
    const int kg   = tid >> 4;          // D rows (kg*4+r) -> unit_local
    const int ex   = e0 + mrow;
    const int ub   = u0 + kg * 4;

    short8 wf0[12], wf1[12], wf2[12], wf3[12];
#pragma unroll
    for (int kk = 0; kk < 12; ++kk) {
        wf0[kk] = *(const short8*)&Ws[0][mrow][kk * 32 + kg * 8];
        wf1[kk] = *(const short8*)&Ws[1][mrow][kk * 32 + kg * 8];
        wf2[kk] = *(const short8*)&Ws[2][mrow][kk * 32 + kg * 8];
        wf3[kk] = *(const short8*)&Ws[3][mrow][kk * 32 + kg * 8];
    }
    // PIN: make fragment origins opaque -> no LDS rematerialization in the loop.
#pragma unroll
    for (int kk = 0; kk < 12; ++kk) {
        asm volatile("" : "+v"(wf0[kk]));
        asm volatile("" : "+v"(wf1[kk]));
        asm volatile("" : "+v"(wf2[kk]));
        asm volatile("" : "+v"(wf3[kk]));
    }

    float bsr[4][4];
#pragma unroll
    for (int g = 0; g < 4; ++g)
#pragma unroll
        for (int r = 0; r < 4; ++r) {
            bsr[g][r] = 2.0f * bias[g * HDIM + ub + r];
            asm volatile("" : "+v"(bsr[g][r]));
        }

    const f32x4 Z4 = {0.f, 0.f, 0.f, 0.f};
    float cr[4] = {0.f, 0.f, 0.f, 0.f};

    // coalesced message layout (parity slab = 256 KB)
    const int kgc   = 2 * (i & 1) + (kg >> 1);
    const int mprod = 2 * (i >> 1) + (kg & 1);
    const size_t PSTRIDE  = (size_t)NCOLS * 16384;
    const size_t cons_off = (size_t)j * 16384 + (size_t)kg * 4096 + (size_t)mrow * 16;
    const size_t prod_off = (size_t)j * 16384 + (size_t)kgc * 4096
                          + (size_t)mprod * 256 + (size_t)mrow * 16;

#define X_GATHER(dst, tt)                                                          \
    {                                                                              \
        const float* xb = X + (size_t)ex * NIN * TSTEPS + (tt);                    \
        _Pragma("unroll")                                                          \
        for (int kk = 0; kk < 4; ++kk) {                                           \
            union { __hip_bfloat16 hh[8]; short8 v; } uxx;                         \
            _Pragma("unroll")                                                      \
            for (int e = 0; e < 8; ++e)                                            \
                uxx.hh[e] = (__hip_bfloat16)xb[(size_t)(kk * 32 + kg * 8 + e) * TSTEPS]; \
            (dst)[kk] = uxx.v;                                                     \
        }                                                                          \
    }

    // prologue: x fragments + xa for t=0
    short8 xf[4];
    if (PX) {
        const unsigned short* xrow = xp + ((size_t)0 * NEX + ex) * NIN + kg * 32;
#pragma unroll
        for (int kk = 0; kk < 4; ++kk) xf[kk] = *(const short8*)(xrow + kk * 8);
    } else {
        X_GATHER(xf, 0);
    }
    f32x4 xa0 = Z4, xa1 = Z4, xa2 = Z4, xa3 = Z4;
#pragma unroll
    for (int kk = 0; kk < 4; ++kk) {
        xa0 = __builtin_amdgcn_mfma_f32_16x16x32_bf16(wf0[8 + kk], xf[kk], xa0, 0, 0, 0);
        xa1 = __builtin_amdgcn_mfma_f32_16x16x32_bf16(wf1[8 + kk], xf[kk], xa1, 0, 0, 0);
        xa2 = __builtin_amdgcn_mfma_f32_16x16x32_bf16(wf2[8 + kk], xf[kk], xa2, 0, 0, 0);
        xa3 = __builtin_amdgcn_mfma_f32_16x16x32_bf16(wf3[8 + kk], xf[kk], xa3, 0, 0, 0);
    }

    for (int t = 0; t < TSTEPS; ++t) {
        f32x4 a0 = xa0, a1 = xa1, a2 = xa2, a3 = xa3;   // x part pre-accumulated

        if (t > 0) {
            const char* sb = hbuf2 + (size_t)((t - 1) & 1) * PSTRIDE + cons_off;
            i32x4 m[16];
            for (;;) {
                msg_load16c(sb, m);   // fused poll + data (coalesced, one drain)
                if (__all(tagmin16(m) == (unsigned int)t)) break;
            }
            const unsigned int* mu = (const unsigned int*)m;
#pragma unroll
            for (int kk = 0; kk < 8; ++kk) {
                union { unsigned int u[4]; short8 v; } z;
                z.u[0] = mu[4 * (2 * kk) + 0];
                z.u[1] = mu[4 * (2 * kk) + 2];
                z.u[2] = mu[4 * (2 * kk + 1) + 0];
                z.u[3] = mu[4 * (2 * kk + 1) + 2];
                a0 = __builtin_amdgcn_mfma_f32_16x16x32_bf16(wf0[kk], z.v, a0, 0, 0, 0);
                a1 = __builtin_amdgcn_mfma_f32_16x16x32_bf16(wf1[kk], z.v, a1, 0, 0, 0);
                a2 = __builtin_amdgcn_mfma_f32_16x16x32_bf16(wf2[kk], z.v, a2, 0, 0, 0);
                a3 = __builtin_amdgcn_mfma_f32_16x16x32_bf16(wf3[kk], z.v, a3, 0, 0, 0);
            }
        }

        // ---- pointwise cell ----
        float hr[4];
#pragma unroll
        for (int r = 0; r < 4; ++r) {
            const float gi = sig_(a0[r] + bsr[0][r]);
            const float gf = sig_(a1[r] + bsr[1][r]);
            const float gg = tanh_(a2[r] + bsr[2][r]);
            const float go = sig_(a3[r] + bsr[3][r]);
            cr[r] = gf * cr[r] + gi * gg;
            hr[r] = go * tanh_(cr[r]);
        }

        // ---- publish: ONE 16B dual-tag message (sc0 sc1), coalesced slot ----
        union { unsigned int u[4]; i32x4 i4; } P;
        __hip_bfloat162 p01(__float2bfloat16(hr[0]), __float2bfloat16(hr[1]));
        __hip_bfloat162 p23(__float2bfloat16(hr[2]), __float2bfloat16(hr[3]));
        P.u[0] = *(unsigned int*)&p01;
        P.u[1] = (unsigned int)(t + 1);
        P.u[2] = *(unsigned int*)&p23;
        P.u[3] = (unsigned int)(t + 1);
        char* dst = hbuf2 + (size_t)(t & 1) * PSTRIDE + prod_off;
        asm volatile("global_store_dwordx4 %0, %1, off sc0 sc1"
                     :: "v"(dst), "v"(P.i4) : "memory");

        // ---- shadow: outputs + x(t+1) prefetch + x-MFMAs for t+1 ----
        const size_t off = (size_t)t * NEX * HDIM + (size_t)ex * HDIM + ub;
        *(float4*)&A[off] = make_float4(hr[0], hr[1], hr[2], hr[3]);
        *(float4*)&C[off] = make_float4(cr[0], cr[1], cr[2], cr[3]);
        if (t + 1 < TSTEPS) {
            if (PX) {
                const unsigned short* xrow = xp + ((size_t)(t + 1) * NEX + ex) * NIN + kg * 32;
#pragma unroll
                for (int kk = 0; kk < 4; ++kk) xf[kk] = *(const short8*)(xrow + kk * 8);
            } else {
                X_GATHER(xf, t + 1);
            }
            xa0 = Z4; xa1 = Z4; xa2 = Z4; xa3 = Z4;
#pragma unroll
            for (int kk = 0; kk < 4; ++kk) {
                xa0 = __builtin_amdgcn_mfma_f32_16x16x32_bf16(wf0[8 + kk], xf[kk], xa0, 0, 0, 0);
                xa1 = __builtin_amdgcn_mfma_f32_16x16x32_bf16(wf1[8 + kk], xf[kk], xa1, 0, 0, 0);
                xa2 = __builtin_amdgcn_mfma_f32_16x16x32_bf16(wf2[8 + kk], xf[kk], xa2, 0, 0, 0);
                xa3 = __builtin_amdgcn_mfma_f32_16x16x32_bf16(wf3[8 + kk], xf[kk], xa3, 0, 0, 0);
            }
        }
    }
#undef X_GATHER
}

extern "C" void kernel_launch(void* const* d_in, const int* in_sizes, int n_in,
                              void* d_out, int out_size, void* d_ws, size_t ws_size,
                              hipStream_t stream) {
    const float* X   = (const float*)d_in[0];
    const float* Wih = (const float*)d_in[1];
    const float* Whh = (const float*)d_in[2];
    const float* b   = (const float*)d_in[3];
    float* A = (float*)d_out;
    float* C = A + (size_t)TSTEPS * NEX * HDIM;

    const size_t hbuf_bytes = (size_t)2 * NCOLS * 16384;                           // 512 KB
    const size_t xp_bytes   = (size_t)TSTEPS * NEX * NIN * sizeof(unsigned short); // 32 MB

    char* hbuf2 = (char*)d_ws;
    unsigned short* xpw = (unsigned short*)((char*)d_ws + hbuf_bytes);
    const bool px = ws_size >= hbuf_bytes + xp_bytes;

    const int nzero = (int)(hbuf_bytes / 4);
    zero_ws<<<(nzero + 255) / 256, 256, 0, stream>>>((unsigned int*)hbuf2, nzero);
    if (px) pack_x<<<dim3(NEX * 32), dim3(64), 0, stream>>>(X, xpw);

    const unsigned short* xpc = xpw;
    if (px) {
        void* args[] = {(void*)&X, (void*)&Wih, (void*)&Whh, (void*)&b,
                        (void*)&A, (void*)&C, (void*)&hbuf2, (void*)&xpc};
        hipError_t err = hipLaunchCooperativeKernel((const void*)lstm_persist<1>,
                                                    dim3(256), dim3(64), args, 0, stream);
        if (err != hipSuccess) {
            lstm_persist<1><<<dim3(256), dim3(64), 0, stream>>>(X, Wih, Whh, b, A, C, hbuf2, xpc);
        }
    } else {
        void* args[] = {(void*)&X, (void*)&Wih, (void*)&Whh, (void*)&b,
                        (void*)&A, (void*)&C, (void*)&hbuf2, (void*)&xpc};
        hipError_t err = hipLaunchCooperativeKernel((const void*)lstm_persist<0>,
                                                    dim3(256), dim3(64), args, 0, stream);
        if (err != hipSuccess) {
            lstm_persist<0><<<dim3(256), dim3(64), 0, stream>>>(X, Wih, Whh, b, A, C, hbuf2, xpc);
        }
    }
}